// Round 10
// baseline (18.396 us; speedup 1.0000x reference)
//
#include <hip/hip_runtime.h>

// VQC 16-wire / 10-layer — EXACT tensor-product factorization, two kernels.
//
// _pairs(16) couples only {0,1,14,15} (edges 0-1, 14-15, 15-0) and the six
// pairs {2k,2k+1}, k=1..6. Components never interact =>
//   out[m] = p4[x0 x1 x14 x15] * prod_k p2_k[x_{2k} x_{2k+1}]
// (wire w <-> bit 15-w of amp index m). Verified rounds 7-9 (absmax 3.05e-5).
//
// Round 9 fused factor-computation into every writer block: ~2.5 us of
// sincosf/shfl preamble x 2 blocks/CU serialized ahead of the writes.
// Split:
//   factor_kernel: 128 blocks (1/batch), lane-parallel component sims
//                  (round-9 phase A+B verbatim), 40 floats/batch -> fac.
//   expand_kernel: 2048 blocks x 256 thr (8/CU), preamble = 40 L2-hit loads,
//                  then pure lane-contiguous streaming stores (33.5 MB).

#define NB 128
#define NL 10

// U = RZ(tz) RY(ty) RX(tx);  u10 = -conj(u01), u11 = conj(u00).
__device__ __forceinline__ void getU(const float* __restrict__ p,
                                     float& u00r, float& u00i,
                                     float& u01r, float& u01i) {
    float sx, cx, sy, cy, sz, cz;
    sincosf(0.5f * p[0], &sx, &cx);
    sincosf(0.5f * p[1], &sy, &cy);
    sincosf(0.5f * p[2], &sz, &cz);
    u00r =  cz * cy * cx + sz * sy * sx;
    u00i =  cz * sy * sx - sz * cy * cx;
    u01r = -cz * sy * cx - sz * cy * sx;
    u01i = -cz * cy * sx + sz * sy * cx;
}

// fac layout per batch (64-float stride): [0..15] p4 (idx = x0<<3|x1<<2|x14<<1|x15),
// [16+4k .. 16+4k+3] p2_k (idx = x_{2k+2}<<1 | x_{2k+3}), k = 0..5.
__global__ __launch_bounds__(256, 4) void factor_kernel(const float* __restrict__ params,
                                                        float* __restrict__ fac) {
    const int bb = blockIdx.x;
    const int t  = threadIdx.x;

    __shared__ float4 Us[NL * 16];

    // ---- Phase A: all 160 gate matrices in parallel ----
    if (t < NL * 16) {
        const int L = t >> 4, w = t & 15;
        const float* p = params + bb * (48 * NL) + L * 48 + w * 3;
        float a, b, c, d;
        getU(p, a, b, c, d);
        Us[t] = make_float4(a, b, c, d);
    }
    __syncthreads();

    // ---- Phase B: lane-parallel component sims (wave 0 only) ----
    // Lanes 0..15: 4-qubit comp {0,1,14,15}, one complex amp per lane
    // (basis = x0<<3|x1<<2|x14<<1|x15). Lanes 16..39: six 2-qubit comps,
    // 4 lanes each. CNOT = shfl permutation; rotation = shfl pair exchange.
    if (t < 64) {
        const bool isC0   = (t < 16);
        const bool isPair = (t >= 16 && t < 40);
        const int  k      = isPair ? ((t - 16) >> 2) : 0;
        const int  lb     = isC0 ? t : (t & 3);
        int p1 = t, p2 = t, p3 = t;
        if (isC0) {
            p1 = t ^ ((t & 8) >> 1);   // CN(0,1):  bit3 controls bit2
            p2 = t ^ ((t & 2) >> 1);   // CN(14,15): bit1 controls bit0
            p3 = t ^ ((t & 1) << 3);   // CN(15,0): bit0 controls bit3
        } else if (isPair) {
            p1 = (t & ~3) | (lb ^ ((lb & 2) >> 1));  // CN(c,c+1)
        }
        int m4 = 0, m5 = 0, m6 = 0, m7 = 0;
        int w4 = 0, w5 = 0, w6 = 0, w7 = 0;
        if (isC0)        { m4 = 8; w4 = 0;          m5 = 4; w5 = 1;
                           m6 = 2; w6 = 14;         m7 = 1; w7 = 15; }
        else if (isPair) { m4 = 2; w4 = 2 * k + 2;  m5 = 1; w5 = 2 * k + 3; }

        float vr = (lb == 0 && (isC0 || isPair)) ? 1.f : 0.f;
        float vi = 0.f;

#define PERM(SRC)                         \
    do {                                  \
        vr = __shfl(vr, (SRC), 64);       \
        vi = __shfl(vi, (SRC), 64);       \
    } while (0)
#define ROT(M, W)                                                   \
    do {                                                            \
        const int m_ = (M);                                         \
        float4 U = Us[L * 16 + (W)];                                \
        float prr = __shfl(vr, t ^ m_, 64);                         \
        float pri = __shfl(vi, t ^ m_, 64);                         \
        const bool act = m_ != 0;                                   \
        const bool up  = (lb & m_) == 0;                            \
        float cor = act ? U.x : 1.f;                                \
        float coi = act ? (up ? U.y : -U.y) : 0.f;                  \
        float cpr = act ? (up ? U.z : -U.z) : 0.f;                  \
        float cpi = act ? U.w : 0.f;                                \
        float nr = cor * vr - coi * vi + cpr * prr - cpi * pri;     \
        float ni = cor * vi + coi * vr + cpr * pri + cpi * prr;     \
        vr = nr;                                                    \
        vi = ni;                                                    \
    } while (0)

#pragma unroll 1
        for (int L = 0; L < NL; ++L) {
            PERM(p1);
            PERM(p2);
            PERM(p3);
            ROT(m4, w4);
            ROT(m5, w5);
            ROT(m6, w6);
            ROT(m7, w7);
        }
#undef PERM
#undef ROT
        const float pr = vr * vr + vi * vi;
        if (isC0)        fac[bb * 64 + t] = pr;
        else if (isPair) fac[bb * 64 + 16 + k * 4 + lb] = pr;
    }
}

// 2048 blocks x 256 threads; block = (bb = batch, nib = m[15:12]).
// Thread t = m[9:2]; e = m[11:10]; float4 elems = m[1:0].
//   out4[(bb<<14)|(nib<<10)|(e<<8)|t] =
//     p2_0[nib&3] * p2_1[e] * p2_2[t>>6] * p2_3[(t>>4)&3] * p2_4[(t>>2)&3]
//     * p2_5[t&3] * p4[(nib>>2)<<2 | m[1:0]]
// Each wave store: 64 lanes x 16 B contiguous = 1 KB.
__global__ __launch_bounds__(256, 8) void expand_kernel(const float* __restrict__ fac,
                                                        float* __restrict__ out) {
    const int bb  = blockIdx.x >> 4;
    const int nib = blockIdx.x & 15;
    const int t   = threadIdx.x;

    __shared__ float Lf[40];
    if (t < 40) Lf[t] = fac[bb * 64 + t];
    __syncthreads();

    const float Ft = Lf[24 + (t >> 6)] * Lf[28 + ((t >> 4) & 3)] *
                     Lf[32 + ((t >> 2) & 3)] * Lf[36 + (t & 3)];
    const int p4b = (nib >> 2) << 2;
    const float p40 = Lf[p4b + 0], p41 = Lf[p4b + 1];
    const float p42 = Lf[p4b + 2], p43 = Lf[p4b + 3];
    const float f0 = Lf[16 + (nib & 3)] * Ft;

    float4* ob = (float4*)out + (((size_t)bb << 14) | ((size_t)nib << 10));
#pragma unroll
    for (int e = 0; e < 4; ++e) {
        const float fe = f0 * Lf[20 + e];
        ob[(e << 8) | t] = make_float4(fe * p40, fe * p41, fe * p42, fe * p43);
    }
}

extern "C" void kernel_launch(void* const* d_in, const int* in_sizes, int n_in,
                              void* d_out, int out_size, void* d_ws, size_t ws_size,
                              hipStream_t stream) {
    const float* params = (const float*)d_in[0];
    float* out = (float*)d_out;
    float* fac = (float*)d_ws;  // 128 * 64 floats = 32 KiB

    factor_kernel<<<NB, 256, 0, stream>>>(params, fac);
    expand_kernel<<<2048, 256, 0, stream>>>(fac, out);
}

// Round 11
// 15.525 us; speedup vs baseline: 1.1850x; 1.1850x over previous
//
#include <hip/hip_runtime.h>

// VQC 16-wire / 10-layer — EXACT tensor-product factorization, single kernel.
//
// _pairs(16) couples only {0,1,14,15} (edges 0-1, 14-15, 15-0) and the six
// pairs {2k,2k+1}, k=1..6. Components never interact =>
//   out[m] = p4[x0 x1 x14 x15] * prod_k p2_k[x_{2k} x_{2k+1}]
// (wire w <-> bit 15-w of amp index m). Verified rounds 7-10 (absmax 3.05e-5).
//
// One kernel, 1024 blocks x 256 threads (4 blocks/CU); block = (bb, oct=m[15:13]).
// Phase A: threads 0..159 compute the batch's 160 gate-U's in parallel.
// Phase B: lane-parallel component sims on wave 0. vs round 9: the three CNOT
//          shuffles are composed into ONE permutation sigma = p1.p2.p3 per
//          layer (5 chain steps/layer instead of 7), and the layer loop is
//          fully unrolled so all 40 U ds_reads issue ahead of the VALU chain.
// Phase C: outer-product expansion, factors inlined (no extra barrier);
//          8 x 1 KB/wave contiguous stores per thread-iter; 32 KB/block.

#define NB 128
#define NL 10

// U = RZ(tz) RY(ty) RX(tx);  u10 = -conj(u01), u11 = conj(u00).
__device__ __forceinline__ void getU(const float* __restrict__ p,
                                     float& u00r, float& u00i,
                                     float& u01r, float& u01i) {
    float sx, cx, sy, cy, sz, cz;
    sincosf(0.5f * p[0], &sx, &cx);
    sincosf(0.5f * p[1], &sy, &cy);
    sincosf(0.5f * p[2], &sz, &cz);
    u00r =  cz * cy * cx + sz * sy * sx;
    u00i =  cz * sy * sx - sz * cy * cx;
    u01r = -cz * sy * cx - sz * cy * sx;
    u01i = -cz * cy * sx + sz * sy * cx;
}

__global__ __launch_bounds__(256, 8) void vqc_fused(const float* __restrict__ params,
                                                    float* __restrict__ out) {
    const int bb  = blockIdx.x >> 3;   // batch
    const int oct = blockIdx.x & 7;    // m[15:13]
    const int t   = threadIdx.x;

    __shared__ float4 Us[NL * 16];     // per-gate U (u00r,u00i,u01r,u01i)
    __shared__ float  p4s[16];         // |amp|^2 of 4-qubit comp {0,1,14,15}
    __shared__ float  p2s[6][4];       // |amp|^2 of pair comps (2k+2, 2k+3)

    // ---- Phase A: all 160 gate matrices in parallel ----
    if (t < NL * 16) {
        const int L = t >> 4, w = t & 15;
        const float* p = params + bb * (48 * NL) + L * 48 + w * 3;
        float a, b, c, d;
        getU(p, a, b, c, d);
        Us[t] = make_float4(a, b, c, d);
    }
    __syncthreads();

    // ---- Phase B: lane-parallel component sims (wave 0 only) ----
    // Lanes 0..15: 4-qubit comp {0,1,14,15} (basis = x0<<3|x1<<2|x14<<1|x15).
    // Lanes 16..39: six 2-qubit comps, 4 lanes each (basis = x_c<<1|x_{c+1}).
    // Per layer: ONE composed CNOT gather sigma, then 4 rotation steps.
    if (t < 64) {
        const bool isC0   = (t < 16);
        const bool isPair = (t >= 16 && t < 40);
        const int  k      = isPair ? ((t - 16) >> 2) : 0;
        const int  lb     = isC0 ? t : (t & 3);
        // sigma = p1 . p2 . p3 (gathers compose right-to-left: sigma(t) =
        // p1(p2(p3(t))) applies CN(0,1) first, then CN(14,15), then CN(15,0))
        int sg = t;
        if (isC0) {
            int u = t ^ ((t & 1) << 3);    // p3: CN(15,0), bit0 controls bit3
            int w = u ^ ((u & 2) >> 1);    // p2: CN(14,15), bit1 controls bit0
            sg    = w ^ ((w & 8) >> 1);    // p1: CN(0,1),  bit3 controls bit2
        } else if (isPair) {
            sg = (t & ~3) | (lb ^ ((lb & 2) >> 1));   // CN(c,c+1)
        }
        int m4 = 0, m5 = 0, m6 = 0, m7 = 0;
        int w4 = 0, w5 = 0, w6 = 0, w7 = 0;
        if (isC0)        { m4 = 8; w4 = 0;          m5 = 4; w5 = 1;
                           m6 = 2; w6 = 14;         m7 = 1; w7 = 15; }
        else if (isPair) { m4 = 2; w4 = 2 * k + 2;  m5 = 1; w5 = 2 * k + 3; }

        float vr = (lb == 0 && (isC0 || isPair)) ? 1.f : 0.f;
        float vi = 0.f;

#define ROT(M, W)                                                   \
    do {                                                            \
        const int m_ = (M);                                         \
        float4 U = Us[L * 16 + (W)];                                \
        float prr = __shfl(vr, t ^ m_, 64);                         \
        float pri = __shfl(vi, t ^ m_, 64);                         \
        const bool act = m_ != 0;                                   \
        const bool up  = (lb & m_) == 0;                            \
        float cor = act ? U.x : 1.f;                                \
        float coi = act ? (up ? U.y : -U.y) : 0.f;                  \
        float cpr = act ? (up ? U.z : -U.z) : 0.f;                  \
        float cpi = act ? U.w : 0.f;                                \
        float nr = cor * vr - coi * vi + cpr * prr - cpi * pri;     \
        float ni = cor * vi + coi * vr + cpr * pri + cpi * prr;     \
        vr = nr;                                                    \
        vi = ni;                                                    \
    } while (0)

#pragma unroll
        for (int L = 0; L < NL; ++L) {
            vr = __shfl(vr, sg, 64);   // all CNOTs of the layer, composed
            vi = __shfl(vi, sg, 64);
            ROT(m4, w4);
            ROT(m5, w5);
            ROT(m6, w6);
            ROT(m7, w7);
        }
#undef ROT
        const float pr = vr * vr + vi * vi;
        if (isC0)        p4s[t] = pr;
        else if (isPair) p2s[k][lb] = pr;
    }
    __syncthreads();

    // ---- Phase C: expansion. Per-batch float4 index f = m[15:2]:
    // f[13:11]=oct, f[10:8]=i (m[12:10]), f[7:0]=t (m[9:2]); e = m[1:0].
    //   p4 idx = m15<<3|m14<<2|m1<<1|m0 = ((oct>>1)<<2)|e
    //   p2_0[m13:12] = p2_0[(oct&1)<<1 | i>>2],  p2_1[m11:10] = p2_1[i&3]
    //   p2_2[t>>6], p2_3[(t>>4)&3], p2_4[(t>>2)&3], p2_5[t&3]
    const float Ft = p2s[2][t >> 6] * p2s[3][(t >> 4) & 3] *
                     p2s[4][(t >> 2) & 3] * p2s[5][t & 3];
    const int p4b = (oct >> 1) << 2;
    const float p40 = p4s[p4b + 0], p41 = p4s[p4b + 1];
    const float p42 = p4s[p4b + 2], p43 = p4s[p4b + 3];

    float4* ob = (float4*)out + (((size_t)bb << 14) | ((size_t)oct << 11));
#pragma unroll
    for (int i = 0; i < 8; ++i) {
        const float fe = Ft * p2s[0][((oct & 1) << 1) | (i >> 2)] * p2s[1][i & 3];
        ob[(i << 8) | t] = make_float4(fe * p40, fe * p41, fe * p42, fe * p43);
    }
}

extern "C" void kernel_launch(void* const* d_in, const int* in_sizes, int n_in,
                              void* d_out, int out_size, void* d_ws, size_t ws_size,
                              hipStream_t stream) {
    const float* params = (const float*)d_in[0];
    float* out = (float*)d_out;
    vqc_fused<<<1024, 256, 0, stream>>>(params, out);
}